// Round 14
// baseline (253.545 us; speedup 1.0000x reference)
//
#include <hip/hip_runtime.h>
#include <math.h>

#define NNODES 50000
#define D 256
#define NSAMP 5
#define LN_EPS 1e-5f
#define NB 196           // row buckets of 256 rows: ceil(50000/256)
#define BCAP 9216        // edges per bucket capacity (mean 8192, +11 sigma)
#define ACHUNK 8192      // edges per binA block

typedef __bf16 bf16;
typedef __attribute__((ext_vector_type(8))) __bf16 bf16x8;
typedef __attribute__((ext_vector_type(4))) float f32x4;
typedef unsigned long long u64;

__device__ inline float bflo(unsigned int u) { return __uint_as_float(u << 16); }
__device__ inline float bfhi(unsigned int u) { return __uint_as_float(u & 0xffff0000u); }

__device__ inline u64 packrec(int r, int c, float v) {
    // col:16 | row:16 | valbits:32   (N=50000 < 65536 so both fit 16 bits)
    return (u64)(unsigned int)(c | (r << 16)) | ((u64)__float_as_uint(v) << 32);
}

// ---------------------------------------------------------------------------
// K0: blocks 0..255: wt[n][k] = bf16(w[k][n]); block 256: zero bucket cursors
// ---------------------------------------------------------------------------
__global__ void prep_kernel(const float* __restrict__ w, bf16* __restrict__ wt,
                            int* __restrict__ bcur) {
    const int b = blockIdx.x;
    if (b < D) {
        const int k = threadIdx.x;
        wt[(size_t)b * D + k] = (bf16)w[(size_t)k * D + b];
    } else {
        if (threadIdx.x < NB) bcur[threadIdx.x] = 0;
    }
}

// ---------------------------------------------------------------------------
// K1: standalone pass-A bucket binning, 512 threads/block
// ---------------------------------------------------------------------------
__global__ __launch_bounds__(512) void binA_kernel(const int* __restrict__ rows,
                                                   const int* __restrict__ cols,
                                                   const float* __restrict__ vals,
                                                   int* __restrict__ bcur,
                                                   u64* __restrict__ binned, int E) {
    __shared__ int hist[NB];
    __shared__ int base[NB];
    for (int i = threadIdx.x; i < NB; i += 512) hist[i] = 0;
    __syncthreads();
    const int e0 = blockIdx.x * ACHUNK;
    const int e1 = min(e0 + ACHUNK, E);
    for (int e = e0 + threadIdx.x; e < e1; e += 512)
        atomicAdd(&hist[rows[e] >> 8], 1);
    __syncthreads();
    for (int i = threadIdx.x; i < NB; i += 512) {
        const int c = hist[i];
        base[i] = c ? atomicAdd(&bcur[i], c) : 0;
        hist[i] = 0;                      // reuse as local cursor
    }
    __syncthreads();
    for (int e = e0 + threadIdx.x; e < e1; e += 512) {
        const int r = rows[e];
        const int b = r >> 8;
        const int k = base[b] + atomicAdd(&hist[b], 1);
        if (k < BCAP)                     // statistically unreachable guard
            binned[(size_t)b * BCAP + k] = packrec(r, cols[e], vals[e]);
    }
}

// ---------------------------------------------------------------------------
// K2 (fused): blocks [0, NB): sortB — per-bucket counting sort by row
//             blocks [NB, NB+GB): GEMM h = x @ w via MFMA
// ---------------------------------------------------------------------------
__global__ __launch_bounds__(256) void gemm_sortB_kernel(const float* __restrict__ x,
                                                         const bf16* __restrict__ wt,
                                                         bf16* __restrict__ h,
                                                         const u64* __restrict__ binned,
                                                         const int* __restrict__ bcur,
                                                         u64* __restrict__ sorted,
                                                         int* __restrict__ rstart,
                                                         int* __restrict__ rcnt) {
    if ((int)blockIdx.x < NB) {
        const int b = blockIdx.x;
        const int tid = threadIdx.x;
        const int cnt_b = min(bcur[b], BCAP);
        const u64* src = binned + (size_t)b * BCAP;

        __shared__ int hist[256];
        __shared__ int scn[256];
        hist[tid] = 0;
        __syncthreads();
        for (int i = tid; i < cnt_b; i += 256)
            atomicAdd(&hist[(int)((src[i] >> 16) & 255)], 1);
        __syncthreads();
        const int v = hist[tid];
        scn[tid] = v;
        __syncthreads();
        for (int d = 1; d < 256; d <<= 1) {
            const int t = (tid >= d) ? scn[tid - d] : 0;
            __syncthreads();
            scn[tid] += t;
            __syncthreads();
        }
        const int excl = scn[tid] - v;
        const int r = b * 256 + tid;
        if (r < NNODES) {
            rstart[r] = b * BCAP + excl;
            rcnt[r]   = v;
        }
        hist[tid] = excl;   // reuse as per-row cursor
        __syncthreads();
        for (int i = tid; i < cnt_b; i += 256) {
            const u64 rec = src[i];
            const int k = atomicAdd(&hist[(int)((rec >> 16) & 255)], 1);
            sorted[(size_t)b * BCAP + k] = rec;
        }
        return;
    }

    // ---- GEMM path (identical to validated round-2 kernel) ----
    const int gb = blockIdx.x - NB;
    const int wave = threadIdx.x >> 6;
    const int lane = threadIdx.x & 63;
    const int row0 = gb * 64 + wave * 16;
    const int am = lane & 15;
    const int ag = lane >> 4;

    int arow = row0 + am;
    if (arow >= NNODES) arow = NNODES - 1;

    f32x4 acc[16];
#pragma unroll
    for (int n = 0; n < 16; ++n) acc[n] = (f32x4){0.f, 0.f, 0.f, 0.f};

#pragma unroll
    for (int kk = 0; kk < 8; ++kk) {
        const int kb = kk * 32 + ag * 8;
        const float* xp = x + (size_t)arow * D + kb;
        const f32x4 a0 = __builtin_nontemporal_load((const f32x4*)xp);
        const f32x4 a1 = __builtin_nontemporal_load((const f32x4*)(xp + 4));
        bf16x8 a;
        a[0] = (bf16)a0[0]; a[1] = (bf16)a0[1]; a[2] = (bf16)a0[2]; a[3] = (bf16)a0[3];
        a[4] = (bf16)a1[0]; a[5] = (bf16)a1[1]; a[6] = (bf16)a1[2]; a[7] = (bf16)a1[3];
#pragma unroll
        for (int n = 0; n < 16; ++n) {
            const bf16x8 b = *(const bf16x8*)(wt + (size_t)(n * 16 + am) * D + kb);
            acc[n] = __builtin_amdgcn_mfma_f32_16x16x32_bf16(a, b, acc[n], 0, 0, 0);
        }
    }

    const int drow = row0 + ag * 4;
#pragma unroll
    for (int r = 0; r < 4; ++r) {
        if (drow + r < NNODES) {
            bf16* hp = h + (size_t)(drow + r) * D + am;
#pragma unroll
            for (int n = 0; n < 16; ++n) hp[n * 16] = (bf16)acc[n][r];
        }
    }
}

// ---------------------------------------------------------------------------
// gather helpers
// ---------------------------------------------------------------------------
#define GATHER4(ii) \
    { const u64 e0 = ep[ii], e1 = ep[ii + 1], e2 = ep[ii + 2], e3 = ep[ii + 3]; \
      const uint2 q0 = *(const uint2*)(hb + (size_t)(e0 & 0xFFFF) * D + lane * 4); \
      const uint2 q1 = *(const uint2*)(hb + (size_t)(e1 & 0xFFFF) * D + lane * 4); \
      const uint2 q2 = *(const uint2*)(hb + (size_t)(e2 & 0xFFFF) * D + lane * 4); \
      const uint2 q3 = *(const uint2*)(hb + (size_t)(e3 & 0xFFFF) * D + lane * 4); \
      const float v0 = __uint_as_float((unsigned int)(e0 >> 32)); \
      const float v1 = __uint_as_float((unsigned int)(e1 >> 32)); \
      const float v2 = __uint_as_float((unsigned int)(e2 >> 32)); \
      const float v3 = __uint_as_float((unsigned int)(e3 >> 32)); \
      a0 += v0 * bflo(q0.x) + v1 * bflo(q1.x) + v2 * bflo(q2.x) + v3 * bflo(q3.x); \
      a1 += v0 * bfhi(q0.x) + v1 * bfhi(q1.x) + v2 * bfhi(q2.x) + v3 * bfhi(q3.x); \
      a2 += v0 * bflo(q0.y) + v1 * bflo(q1.y) + v2 * bflo(q2.y) + v3 * bflo(q3.y); \
      a3 += v0 * bfhi(q0.y) + v1 * bfhi(q1.y) + v2 * bfhi(q2.y) + v3 * bfhi(q3.y); }

// ---------------------------------------------------------------------------
// K3: per-row fused SpMM + bias + ELU + LayerNorm + mask-expand
// TWO rows per wave, interleaved 4-edge chunks -> 8 gathers in flight.
// ---------------------------------------------------------------------------
__global__ __launch_bounds__(256) void row_kernel(const unsigned short* __restrict__ hb,
                                                  const int* __restrict__ rstart,
                                                  const int* __restrict__ rcnt,
                                                  const u64* __restrict__ ep,
                                                  const float* __restrict__ bias,
                                                  const float* __restrict__ gamma,
                                                  const float* __restrict__ beta,
                                                  const float* __restrict__ mask,
                                                  float* __restrict__ out, int n) {
    const int wave = threadIdx.x >> 6;
    const int lane = threadIdx.x & 63;
    const int rA = blockIdx.x * 8 + wave * 2;     // this wave's two rows
    const int rB = rA + 1;
    if (rA >= n) return;

    const int sA = rstart[rA];
    const int eA = sA + rcnt[rA];
    const bool hasB = (rB < n);
    const int sB = hasB ? rstart[rB] : 0;
    const int eB = hasB ? sB + rcnt[rB] : 0;

    float A0 = 0.f, A1 = 0.f, A2 = 0.f, A3 = 0.f;   // row A accumulator
    float B0 = 0.f, B1 = 0.f, B2 = 0.f, B3 = 0.f;   // row B accumulator
    int iA = sA, iB = sB;

    // interleaved main loop: 8 broadcast ep loads + 8 independent gathers
    while (iA + 3 < eA && iB + 3 < eB) {
        { float a0 = A0, a1 = A1, a2 = A2, a3 = A3;
          const u64 f0 = ep[iA], f1 = ep[iA+1], f2 = ep[iA+2], f3 = ep[iA+3];
          const u64 g0 = ep[iB], g1 = ep[iB+1], g2 = ep[iB+2], g3 = ep[iB+3];
          const uint2 p0 = *(const uint2*)(hb + (size_t)(f0 & 0xFFFF) * D + lane * 4);
          const uint2 p1 = *(const uint2*)(hb + (size_t)(f1 & 0xFFFF) * D + lane * 4);
          const uint2 p2 = *(const uint2*)(hb + (size_t)(f2 & 0xFFFF) * D + lane * 4);
          const uint2 p3 = *(const uint2*)(hb + (size_t)(f3 & 0xFFFF) * D + lane * 4);
          const uint2 q0 = *(const uint2*)(hb + (size_t)(g0 & 0xFFFF) * D + lane * 4);
          const uint2 q1 = *(const uint2*)(hb + (size_t)(g1 & 0xFFFF) * D + lane * 4);
          const uint2 q2 = *(const uint2*)(hb + (size_t)(g2 & 0xFFFF) * D + lane * 4);
          const uint2 q3 = *(const uint2*)(hb + (size_t)(g3 & 0xFFFF) * D + lane * 4);
          const float u0 = __uint_as_float((unsigned int)(f0 >> 32));
          const float u1 = __uint_as_float((unsigned int)(f1 >> 32));
          const float u2 = __uint_as_float((unsigned int)(f2 >> 32));
          const float u3 = __uint_as_float((unsigned int)(f3 >> 32));
          const float w0 = __uint_as_float((unsigned int)(g0 >> 32));
          const float w1 = __uint_as_float((unsigned int)(g1 >> 32));
          const float w2 = __uint_as_float((unsigned int)(g2 >> 32));
          const float w3 = __uint_as_float((unsigned int)(g3 >> 32));
          a0 += u0 * bflo(p0.x) + u1 * bflo(p1.x) + u2 * bflo(p2.x) + u3 * bflo(p3.x);
          a1 += u0 * bfhi(p0.x) + u1 * bfhi(p1.x) + u2 * bfhi(p2.x) + u3 * bfhi(p3.x);
          a2 += u0 * bflo(p0.y) + u1 * bflo(p1.y) + u2 * bflo(p2.y) + u3 * bflo(p3.y);
          a3 += u0 * bfhi(p0.y) + u1 * bfhi(p1.y) + u2 * bfhi(p2.y) + u3 * bfhi(p3.y);
          B0 += w0 * bflo(q0.x) + w1 * bflo(q1.x) + w2 * bflo(q2.x) + w3 * bflo(q3.x);
          B1 += w0 * bfhi(q0.x) + w1 * bfhi(q1.x) + w2 * bfhi(q2.x) + w3 * bfhi(q3.x);
          B2 += w0 * bflo(q0.y) + w1 * bflo(q1.y) + w2 * bflo(q2.y) + w3 * bflo(q3.y);
          B3 += w0 * bfhi(q0.y) + w1 * bfhi(q1.y) + w2 * bfhi(q2.y) + w3 * bfhi(q3.y);
          A0 = a0; A1 = a1; A2 = a2; A3 = a3; }
        iA += 4; iB += 4;
    }
    // row-A tail
    { float a0 = A0, a1 = A1, a2 = A2, a3 = A3;
      for (; iA + 3 < eA; iA += 4) GATHER4(iA);
      for (; iA < eA; ++iA) {
          const u64 e0 = ep[iA];
          const uint2 q0 = *(const uint2*)(hb + (size_t)(e0 & 0xFFFF) * D + lane * 4);
          const float v0 = __uint_as_float((unsigned int)(e0 >> 32));
          a0 += v0 * bflo(q0.x); a1 += v0 * bfhi(q0.x);
          a2 += v0 * bflo(q0.y); a3 += v0 * bfhi(q0.y);
      }
      A0 = a0; A1 = a1; A2 = a2; A3 = a3; }
    // row-B tail
    { float a0 = B0, a1 = B1, a2 = B2, a3 = B3;
      for (; iB + 3 < eB; iB += 4) GATHER4(iB);
      for (; iB < eB; ++iB) {
          const u64 e0 = ep[iB];
          const uint2 q0 = *(const uint2*)(hb + (size_t)(e0 & 0xFFFF) * D + lane * 4);
          const float v0 = __uint_as_float((unsigned int)(e0 >> 32));
          a0 += v0 * bflo(q0.x); a1 += v0 * bfhi(q0.x);
          a2 += v0 * bflo(q0.y); a3 += v0 * bfhi(q0.y);
      }
      B0 = a0; B1 = a1; B2 = a2; B3 = a3; }

    const f32x4 b4  = *(const f32x4*)(bias + lane * 4);
    const f32x4 g4  = *(const f32x4*)(gamma + lane * 4);
    const f32x4 be4 = *(const f32x4*)(beta + lane * 4);

#pragma unroll
    for (int half = 0; half < 2; ++half) {
        const int r = half ? rB : rA;
        if (half && !hasB) break;
        float x0 = (half ? B0 : A0) + b4[0];
        float x1 = (half ? B1 : A1) + b4[1];
        float x2 = (half ? B2 : A2) + b4[2];
        float x3 = (half ? B3 : A3) + b4[3];
        x0 = x0 > 0.f ? x0 : expm1f(x0);
        x1 = x1 > 0.f ? x1 : expm1f(x1);
        x2 = x2 > 0.f ? x2 : expm1f(x2);
        x3 = x3 > 0.f ? x3 : expm1f(x3);

        float s1 = x0 + x1 + x2 + x3;
        float s2 = x0 * x0 + x1 * x1 + x2 * x2 + x3 * x3;
#pragma unroll
        for (int d = 1; d < 64; d <<= 1) {
            s1 += __shfl_xor(s1, d);
            s2 += __shfl_xor(s2, d);
        }
        const float mu   = s1 * (1.f / 256.f);
        const float var  = s2 * (1.f / 256.f) - mu * mu;
        const float rsig = rsqrtf(var + LN_EPS);

        const float y0 = (x0 - mu) * rsig * g4[0] + be4[0];
        const float y1 = (x1 - mu) * rsig * g4[1] + be4[1];
        const float y2 = (x2 - mu) * rsig * g4[2] + be4[2];
        const float y3 = (x3 - mu) * rsig * g4[3] + be4[3];

#pragma unroll
        for (int smp = 0; smp < NSAMP; ++smp) {
            const f32x4 m4 = *(const f32x4*)(mask + smp * D + lane * 4);
            f32x4 o;
            o[0] = y0 * m4[0];
            o[1] = y1 * m4[1];
            o[2] = y2 * m4[2];
            o[3] = y3 * m4[3];
            __builtin_nontemporal_store(o, (f32x4*)(out + ((size_t)r * NSAMP + smp) * D + lane * 4));
        }
    }
}

// ---------------------------------------------------------------------------
extern "C" void kernel_launch(void* const* d_in, const int* in_sizes, int n_in,
                              void* d_out, int out_size, void* d_ws, size_t ws_size,
                              hipStream_t stream) {
    const float* x     = (const float*)d_in[0];
    const int*   adj   = (const int*)d_in[1];   // [2][E]: rows then cols
    const float* vals  = (const float*)d_in[2];
    const float* mask  = (const float*)d_in[3];
    const float* w     = (const float*)d_in[4];
    const float* bias  = (const float*)d_in[5];
    const float* gamma = (const float*)d_in[6];
    const float* beta  = (const float*)d_in[7];
    float*       out   = (float*)d_out;

    const int N = NNODES;
    const int E = in_sizes[2];
    const int GB = (N + 63) / 64;                 // gemm blocks (782)
    const int AB = (E + ACHUNK - 1) / ACHUNK;     // binA blocks (196)

    // workspace layout: 25.6 + 14.45 + 14.45 + 0.13 + 0.4 = ~55.0 MB
    char* ws = (char*)d_ws;
    unsigned short* hb     = (unsigned short*)ws;                       // 25.6 MB
    u64*            sorted = (u64*)(hb + (size_t)N * D);                // 14.45 MB
    u64*            binned = sorted + (size_t)NB * BCAP;                // 14.45 MB
    bf16*           wt     = (bf16*)(binned + (size_t)NB * BCAP);       // 128 KB
    int*            bcur   = (int*)((char*)wt + (size_t)D * D * 2);     // 1 KB
    int*            rstart = bcur + 256;                                // 200 KB
    int*            rcnt   = rstart + N;                                // 200 KB

    prep_kernel<<<D + 1, 256, 0, stream>>>(w, wt, bcur);
    binA_kernel<<<AB, 512, 0, stream>>>(adj, adj + E, vals, bcur, binned, E);
    gemm_sortB_kernel<<<NB + GB, 256, 0, stream>>>(x, wt, (bf16*)hb,
                                                   binned, bcur, sorted, rstart, rcnt);
    row_kernel<<<(N + 7) / 8, 256, 0, stream>>>(hb, rstart, rcnt, sorted,
                                                bias, gamma, beta, mask, out, N);
}

// Round 15
// 252.116 us; speedup vs baseline: 1.0057x; 1.0057x over previous
//
#include <hip/hip_runtime.h>
#include <math.h>

#define NNODES 50000
#define D 256
#define NSAMP 5
#define LN_EPS 1e-5f
#define NB 196           // row buckets of 256 rows: ceil(50000/256)
#define BCAP 9216        // edges per bucket capacity (mean 8192, +11 sigma)
#define ACHUNK 8192      // edges per binA block

typedef __bf16 bf16;
typedef __attribute__((ext_vector_type(8))) __bf16 bf16x8;
typedef __attribute__((ext_vector_type(4))) float f32x4;
typedef unsigned long long u64;
typedef unsigned int u32;

__device__ inline float bflo(u32 u) { return __uint_as_float(u << 16); }
__device__ inline float bfhi(u32 u) { return __uint_as_float(u & 0xffff0000u); }

__device__ inline u64 packrec(int r, int c, float v) {
    // col:16 | row:16 | valbits:32   (N=50000 < 65536 so both fit 16 bits)
    return (u64)(u32)(c | (r << 16)) | ((u64)__float_as_uint(v) << 32);
}

// ---------------------------------------------------------------------------
// K0: LDS tile transpose w[k][n] fp32 -> wt[n][k] bf16 (coalesced both sides)
// 16 blocks of 256 threads; 64x64 tiles.
// ---------------------------------------------------------------------------
__global__ __launch_bounds__(256) void prep_t_kernel(const float* __restrict__ w,
                                                     bf16* __restrict__ wt) {
    __shared__ float t[64][65];
    const int bi = blockIdx.x >> 2;     // k-tile
    const int bj = blockIdx.x & 3;      // n-tile
    const int tid = threadIdx.x;
#pragma unroll
    for (int it = 0; it < 16; ++it) {
        const int krow = (tid >> 6) + it * 4;
        const int ncol = tid & 63;
        t[krow][ncol] = w[(size_t)(bi * 64 + krow) * D + (bj * 64 + ncol)];
    }
    __syncthreads();
#pragma unroll
    for (int it = 0; it < 16; ++it) {
        const int nrow = (tid >> 6) + it * 4;
        const int kcol = tid & 63;
        wt[(size_t)(bj * 64 + nrow) * D + (bi * 64 + kcol)] = (bf16)t[kcol][nrow];
    }
}

// ---------------------------------------------------------------------------
// K1 (fused): blocks [0, AB): binA bucket binning (bulk, LDS histogram,
//             196 global atomics/block) — latency hides under GEMM waves.
//             blocks [AB, AB+GB): GEMM h = x @ w via MFMA.
// ---------------------------------------------------------------------------
__global__ __launch_bounds__(256) void gemm_binA_kernel(const float* __restrict__ x,
                                                        const bf16* __restrict__ wt,
                                                        bf16* __restrict__ h,
                                                        const int* __restrict__ rows,
                                                        const int* __restrict__ cols,
                                                        const float* __restrict__ vals,
                                                        int* __restrict__ bcur,
                                                        u64* __restrict__ binned,
                                                        int AB, int E) {
    if ((int)blockIdx.x < AB) {
        __shared__ int hist[NB];
        __shared__ int base[NB];
        for (int i = threadIdx.x; i < NB; i += 256) hist[i] = 0;
        __syncthreads();
        const int e0 = blockIdx.x * ACHUNK;
        const int e1 = min(e0 + ACHUNK, E);
        for (int e = e0 + threadIdx.x; e < e1; e += 256)
            atomicAdd(&hist[rows[e] >> 8], 1);
        __syncthreads();
        for (int i = threadIdx.x; i < NB; i += 256) {
            const int c = hist[i];
            base[i] = c ? atomicAdd(&bcur[i], c) : 0;
            hist[i] = 0;                      // reuse as local cursor
        }
        __syncthreads();
        for (int e = e0 + threadIdx.x; e < e1; e += 256) {
            const int r = rows[e];
            const int b = r >> 8;
            const int k = base[b] + atomicAdd(&hist[b], 1);
            if (k < BCAP)                     // statistically unreachable guard
                binned[(size_t)b * BCAP + k] = packrec(r, cols[e], vals[e]);
        }
        return;
    }

    // ---- GEMM path (identical to validated round-2 kernel) ----
    const int gb = blockIdx.x - AB;
    const int wave = threadIdx.x >> 6;
    const int lane = threadIdx.x & 63;
    const int row0 = gb * 64 + wave * 16;
    const int am = lane & 15;
    const int ag = lane >> 4;

    int arow = row0 + am;
    if (arow >= NNODES) arow = NNODES - 1;

    f32x4 acc[16];
#pragma unroll
    for (int n = 0; n < 16; ++n) acc[n] = (f32x4){0.f, 0.f, 0.f, 0.f};

#pragma unroll
    for (int kk = 0; kk < 8; ++kk) {
        const int kb = kk * 32 + ag * 8;
        const float* xp = x + (size_t)arow * D + kb;
        const f32x4 a0 = __builtin_nontemporal_load((const f32x4*)xp);
        const f32x4 a1 = __builtin_nontemporal_load((const f32x4*)(xp + 4));
        bf16x8 a;
        a[0] = (bf16)a0[0]; a[1] = (bf16)a0[1]; a[2] = (bf16)a0[2]; a[3] = (bf16)a0[3];
        a[4] = (bf16)a1[0]; a[5] = (bf16)a1[1]; a[6] = (bf16)a1[2]; a[7] = (bf16)a1[3];
#pragma unroll
        for (int n = 0; n < 16; ++n) {
            const bf16x8 b = *(const bf16x8*)(wt + (size_t)(n * 16 + am) * D + kb);
            acc[n] = __builtin_amdgcn_mfma_f32_16x16x32_bf16(a, b, acc[n], 0, 0, 0);
        }
    }

    const int drow = row0 + ag * 4;
#pragma unroll
    for (int r = 0; r < 4; ++r) {
        if (drow + r < NNODES) {
            bf16* hp = h + (size_t)(drow + r) * D + am;
#pragma unroll
            for (int n = 0; n < 16; ++n) hp[n * 16] = (bf16)acc[n][r];
        }
    }
}

// ---------------------------------------------------------------------------
// K2 sortB: per-bucket counting sort by row; emits u32 records (col | bf16val)
// ---------------------------------------------------------------------------
__global__ __launch_bounds__(256) void sortB_kernel(const u64* __restrict__ binned,
                                                    const int* __restrict__ bcur,
                                                    u32* __restrict__ sorted,
                                                    int* __restrict__ rstart,
                                                    int* __restrict__ rcnt) {
    const int b = blockIdx.x;
    const int tid = threadIdx.x;
    const int cnt_b = min(bcur[b], BCAP);
    const u64* src = binned + (size_t)b * BCAP;

    __shared__ int hist[256];
    __shared__ int scn[256];
    hist[tid] = 0;
    __syncthreads();
    for (int i = tid; i < cnt_b; i += 256)
        atomicAdd(&hist[(int)((src[i] >> 16) & 255)], 1);
    __syncthreads();
    const int v = hist[tid];
    scn[tid] = v;
    __syncthreads();
    for (int d = 1; d < 256; d <<= 1) {
        const int t = (tid >= d) ? scn[tid - d] : 0;
        __syncthreads();
        scn[tid] += t;
        __syncthreads();
    }
    const int excl = scn[tid] - v;
    const int r = b * 256 + tid;
    if (r < NNODES) {
        rstart[r] = b * BCAP + excl;
        rcnt[r]   = v;
    }
    hist[tid] = excl;   // reuse as per-row cursor
    __syncthreads();
    for (int i = tid; i < cnt_b; i += 256) {
        const u64 rec = src[i];
        const int k = atomicAdd(&hist[(int)((rec >> 16) & 255)], 1);
        const float vf = __uint_as_float((u32)(rec >> 32));
        const u32 vb = __float_as_uint((float)(bf16)vf) & 0xffff0000u;  // RNE bf16
        sorted[(size_t)b * BCAP + k] = (u32)(rec & 0xFFFF) | vb;
    }
}

// ---------------------------------------------------------------------------
// K3: per-row fused SpMM(bf16 h, CSR-u32) + bias + ELU + LayerNorm + expand
// one wave per row; lane l owns dims [4l, 4l+3]  (round-13 validated body)
// ---------------------------------------------------------------------------
__global__ __launch_bounds__(256) void row_kernel(const unsigned short* __restrict__ hb,
                                                  const int* __restrict__ rstart,
                                                  const int* __restrict__ rcnt,
                                                  const u32* __restrict__ ep,
                                                  const float* __restrict__ bias,
                                                  const float* __restrict__ gamma,
                                                  const float* __restrict__ beta,
                                                  const float* __restrict__ mask,
                                                  float* __restrict__ out, int n) {
    const int wave = threadIdx.x >> 6;
    const int lane = threadIdx.x & 63;
    const int r = blockIdx.x * 4 + wave;
    if (r >= n) return;

    const int s = rstart[r];
    const int e = s + rcnt[r];

    float a0 = 0.f, a1 = 0.f, a2 = 0.f, a3 = 0.f;
    int i = s;
    for (; i + 3 < e; i += 4) {
        const u32 e0 = ep[i], e1 = ep[i + 1], e2 = ep[i + 2], e3 = ep[i + 3];
        const uint2 q0 = *(const uint2*)(hb + (size_t)(e0 & 0xFFFF) * D + lane * 4);
        const uint2 q1 = *(const uint2*)(hb + (size_t)(e1 & 0xFFFF) * D + lane * 4);
        const uint2 q2 = *(const uint2*)(hb + (size_t)(e2 & 0xFFFF) * D + lane * 4);
        const uint2 q3 = *(const uint2*)(hb + (size_t)(e3 & 0xFFFF) * D + lane * 4);
        const float v0 = bfhi(e0), v1 = bfhi(e1), v2 = bfhi(e2), v3 = bfhi(e3);
        a0 += v0 * bflo(q0.x) + v1 * bflo(q1.x) + v2 * bflo(q2.x) + v3 * bflo(q3.x);
        a1 += v0 * bfhi(q0.x) + v1 * bfhi(q1.x) + v2 * bfhi(q2.x) + v3 * bfhi(q3.x);
        a2 += v0 * bflo(q0.y) + v1 * bflo(q1.y) + v2 * bflo(q2.y) + v3 * bflo(q3.y);
        a3 += v0 * bfhi(q0.y) + v1 * bfhi(q1.y) + v2 * bfhi(q2.y) + v3 * bfhi(q3.y);
    }
    for (; i < e; ++i) {
        const u32 e0 = ep[i];
        const uint2 q0 = *(const uint2*)(hb + (size_t)(e0 & 0xFFFF) * D + lane * 4);
        const float v0 = bfhi(e0);
        a0 += v0 * bflo(q0.x);
        a1 += v0 * bfhi(q0.x);
        a2 += v0 * bflo(q0.y);
        a3 += v0 * bfhi(q0.y);
    }

    // bias + ELU
    const f32x4 b4 = *(const f32x4*)(bias + lane * 4);
    float x0 = a0 + b4[0], x1 = a1 + b4[1], x2 = a2 + b4[2], x3 = a3 + b4[3];
    x0 = x0 > 0.f ? x0 : expm1f(x0);
    x1 = x1 > 0.f ? x1 : expm1f(x1);
    x2 = x2 > 0.f ? x2 : expm1f(x2);
    x3 = x3 > 0.f ? x3 : expm1f(x3);

    // LayerNorm over 256 dims
    float s1 = x0 + x1 + x2 + x3;
    float s2 = x0 * x0 + x1 * x1 + x2 * x2 + x3 * x3;
#pragma unroll
    for (int d = 1; d < 64; d <<= 1) {
        s1 += __shfl_xor(s1, d);
        s2 += __shfl_xor(s2, d);
    }
    const float mu   = s1 * (1.f / 256.f);
    const float var  = s2 * (1.f / 256.f) - mu * mu;
    const float rsig = rsqrtf(var + LN_EPS);

    const f32x4 g4  = *(const f32x4*)(gamma + lane * 4);
    const f32x4 be4 = *(const f32x4*)(beta + lane * 4);
    const float y0 = (x0 - mu) * rsig * g4[0] + be4[0];
    const float y1 = (x1 - mu) * rsig * g4[1] + be4[1];
    const float y2 = (x2 - mu) * rsig * g4[2] + be4[2];
    const float y3 = (x3 - mu) * rsig * g4[3] + be4[3];

#pragma unroll
    for (int smp = 0; smp < NSAMP; ++smp) {
        const f32x4 m4 = *(const f32x4*)(mask + smp * D + lane * 4);
        f32x4 o;
        o[0] = y0 * m4[0];
        o[1] = y1 * m4[1];
        o[2] = y2 * m4[2];
        o[3] = y3 * m4[3];
        __builtin_nontemporal_store(o, (f32x4*)(out + ((size_t)r * NSAMP + smp) * D + lane * 4));
    }
}

// ---------------------------------------------------------------------------
extern "C" void kernel_launch(void* const* d_in, const int* in_sizes, int n_in,
                              void* d_out, int out_size, void* d_ws, size_t ws_size,
                              hipStream_t stream) {
    const float* x     = (const float*)d_in[0];
    const int*   adj   = (const int*)d_in[1];   // [2][E]: rows then cols
    const float* vals  = (const float*)d_in[2];
    const float* mask  = (const float*)d_in[3];
    const float* w     = (const float*)d_in[4];
    const float* bias  = (const float*)d_in[5];
    const float* gamma = (const float*)d_in[6];
    const float* beta  = (const float*)d_in[7];
    float*       out   = (float*)d_out;

    const int N = NNODES;
    const int E = in_sizes[2];
    const int GB = (N + 63) / 64;                 // gemm blocks (782)
    const int AB = (E + ACHUNK - 1) / ACHUNK;     // binA blocks (196)

    // workspace layout: 25.6 + 7.23 + 14.45 + 0.13 + 0.4 = ~47.8 MB
    char* ws = (char*)d_ws;
    unsigned short* hb     = (unsigned short*)ws;                       // 25.6 MB
    u32*            sorted = (u32*)(hb + (size_t)N * D);                // 7.23 MB
    u64*            binned = (u64*)(sorted + (size_t)NB * BCAP);        // 14.45 MB
    bf16*           wt     = (bf16*)(binned + (size_t)NB * BCAP);       // 128 KB
    int*            bcur   = (int*)((char*)wt + (size_t)D * D * 2);     // 1 KB
    int*            rstart = bcur + 256;                                // 200 KB
    int*            rcnt   = rstart + N;                                // 200 KB

    hipMemsetAsync(bcur, 0, 256 * sizeof(int), stream);
    prep_t_kernel<<<16, 256, 0, stream>>>(w, wt);
    gemm_binA_kernel<<<AB + GB, 256, 0, stream>>>(x, wt, (bf16*)hb,
                                                  adj, adj + E, vals, bcur, binned, AB, E);
    sortB_kernel<<<NB, 256, 0, stream>>>(binned, bcur, sorted, rstart, rcnt);
    row_kernel<<<(N + 3) / 4, 256, 0, stream>>>(hb, rstart, rcnt, sorted,
                                                bias, gamma, beta, mask, out, N);
}